// Round 7
// baseline (1266.945 us; speedup 1.0000x reference)
//
#include <hip/hip_runtime.h>

#define HID 2048
#define NE_ 32
#define EW_ 2944
#define ORIG_ 2880
#define TOPK_ 4
#define TD_ 8
#define MAXNNZ_ 256
#define BS_ 1024
#define NEWTOT (NE_*EW_)
#define LDSP 40   // padded row stride in halves: 80B -> conflict-free 2-way

typedef unsigned short u16;
typedef _Float16 h8  __attribute__((ext_vector_type(8)));
typedef float  f32x4 __attribute__((ext_vector_type(4)));
typedef float  fv4   __attribute__((ext_vector_type(4)));
typedef short  s16x8 __attribute__((ext_vector_type(8)));

__device__ __forceinline__ float h2f_bits(u16 u){
  union{ _Float16 h; u16 u; } c; c.u = u; return (float)c.h;
}
__device__ __forceinline__ u16 f2h_bits(float f){
  union{ _Float16 h; u16 u; } c; c.h = (_Float16)f; return c.u;
}
__device__ __forceinline__ float f16q(float f){ return (float)(_Float16)f; }

__device__ __forceinline__ h8 cvt8(fv4 a, fv4 b){
  h8 r;
  r[0]=(_Float16)a[0]; r[1]=(_Float16)a[1]; r[2]=(_Float16)a[2]; r[3]=(_Float16)a[3];
  r[4]=(_Float16)b[0]; r[5]=(_Float16)b[1]; r[6]=(_Float16)b[2]; r[7]=(_Float16)b[3];
  return r;
}
// padded LDS index (halfword units) for [128][32]-f16 tiles, stride 40
__device__ __forceinline__ int ldsx(int row, int q8){ return row*LDSP + q8*8; }

// ---------------- gating: f32 in, f16-quantized logits, top4 ----------------
__global__ __launch_bounds__(256) void k_gate(const float* __restrict__ x,
                                              const float* __restrict__ gw,
                                              float* __restrict__ rw,
                                              float* __restrict__ rwf,
                                              int* __restrict__ counts)
{
  __shared__ float slog[4][NE_];
  const int tid = threadIdx.x, wid = tid>>6, lane = tid&63;
  const int n = blockIdx.x*4 + wid;
  const float* xr = x + (size_t)n*HID + lane*32;
  float xf[32];
  #pragma unroll
  for (int i=0;i<8;i++){
    fv4 v = *(const fv4*)(xr + i*4);
    #pragma unroll
    for (int j=0;j<4;j++) xf[i*4+j] = v[j];
  }
  for (int e=0;e<NE_;e++){
    const float* gr = gw + (size_t)e*HID + lane*32;
    float p = 0.f;
    #pragma unroll
    for (int i=0;i<8;i++){
      fv4 v = *(const fv4*)(gr + i*4);
      #pragma unroll
      for (int j=0;j<4;j++) p += xf[i*4+j]*v[j];
    }
    #pragma unroll
    for (int s=32;s>0;s>>=1) p += __shfl_xor(p, s);
    if (lane==0) slog[wid][e] = f16q(p);   // reference rounds matmul to f16
  }
  if (lane==0){
    float mx=-1e30f;
    for (int e=0;e<NE_;e++) mx = fmaxf(mx, slog[wid][e]);
    float pr[NE_]; float sum=0.f;
    for (int e=0;e<NE_;e++){ float v=__expf(slog[wid][e]-mx); pr[e]=v; sum+=v; }
    for (int e=0;e<NE_;e++) pr[e] = pr[e]/sum;
    int   idx[TOPK_]; float val[TOPK_]; bool used[NE_];
    for (int e=0;e<NE_;e++) used[e]=false;
    float vs=0.f;
    for (int k=0;k<TOPK_;k++){
      float best=-1.f; int bi=0;
      for (int e=0;e<NE_;e++) if(!used[e] && pr[e]>best){best=pr[e];bi=e;}
      used[bi]=true; idx[k]=bi; val[k]=best; vs+=best;
    }
    float* rwr  = rw  + (size_t)n*NE_;
    float* rwfr = rwf + (size_t)n*NE_;
    for (int k=0;k<TOPK_;k++){
      float vraw = val[k]/vs;
      float q = f16q(vraw);            // reference: rw = sparse_rw.astype(f16)
      rwr[idx[k]]  = q;
      rwfr[idx[k]] = vraw;             // f32, for top-256 ranking (matches jax)
      if (q!=0.f) atomicAdd(counts+idx[k], 1);
    }
  }
}

// ---------------- rank experts by count (desc), tie -> lower index ----------
__global__ void k_rank(const int* __restrict__ counts, int* __restrict__ cdcs)
{
  if (threadIdx.x==0){
    int cnt[NE_]; bool used[NE_];
    for (int e=0;e<NE_;e++){ cnt[e]=counts[e]; used[e]=false; }
    for (int k=0;k<16;k++){
      int best=-1, bi=0;
      for (int e=0;e<NE_;e++) if(!used[e] && cnt[e]>best){best=cnt[e];bi=e;}
      used[bi]=true; cdcs[k]=bi;
    }
  }
}

// ------------ per sparse expert: exact top-256 tokens by (v desc, i asc) ----
__global__ __launch_bounds__(256) void k_select(const float* __restrict__ rwf,
                                                const int* __restrict__ cdcs,
                                                int* __restrict__ tok)
{
  __shared__ float v[BS_];
  const int s = blockIdx.x;
  const int e = cdcs[8+s];
  const int tid = threadIdx.x;
  for (int i=tid;i<BS_;i+=256) v[i] = rwf[(size_t)i*NE_ + e];
  __syncthreads();
  for (int i=tid;i<BS_;i+=256){
    float vi=v[i]; int r=0;
    for (int m=0;m<BS_;m++){
      float vm=v[m];
      r += (vm>vi) || (vm==vi && m<i);
    }
    if (r<MAXNNZ_) tok[s*MAXNNZ_+r]=i;
  }
}

// ---------------- up / gate+act GEMM (C = A @ B^T), 128x128 tile, f16 MFMA --
template<bool IS_GATE, bool GATHER>
__global__ __launch_bounds__(256) void k_upgate(const float* __restrict__ x,
                                                const float* __restrict__ w,
                                                const float* __restrict__ bias,
                                                const float* __restrict__ rw,
                                                const int* __restrict__ cdcs,
                                                const int* __restrict__ tok,
                                                u16* __restrict__ act)
{
  __shared__ __align__(16) u16 ldsA[128*LDSP];
  __shared__ __align__(16) u16 ldsB[128*LDSP];
  const int tid=threadIdx.x, lane=tid&63, wid=tid>>6;
  const int bx=blockIdx.x, by=blockIdx.y, t=blockIdx.z;
  const int expert = cdcs[GATHER ? 8+t : t];
  const int srow = tid>>2, q8 = tid&3;           // q8: which 8-elem k-chunk
  const int arow0 = by*128 + srow, arow1 = arow0 + 64;
  const int tok0 = GATHER ? tok[t*MAXNNZ_ + arow0] : arow0;
  const int tok1 = GATHER ? tok[t*MAXNNZ_ + arow1] : arow1;
  const float* aptr0 = x + (size_t)tok0*HID + q8*8;
  const float* aptr1 = x + (size_t)tok1*HID + q8*8;
  const float* bptr0 = w + ((size_t)expert*EW_ + bx*128 + srow)*HID + q8*8;
  const float* bptr1 = bptr0 + (size_t)64*HID;

  f32x4 acc[4][4];
  #pragma unroll
  for (int i=0;i<4;i++)
    #pragma unroll
    for (int j=0;j<4;j++)
      #pragma unroll
      for (int q=0;q<4;q++) acc[i][j][q]=0.f;

  const int wr=wid>>1, wc=wid&1;
  fv4 a0l=*(const fv4*)aptr0, a0h=*(const fv4*)(aptr0+4);
  fv4 a1l=*(const fv4*)aptr1, a1h=*(const fv4*)(aptr1+4);
  fv4 b0l=*(const fv4*)bptr0, b0h=*(const fv4*)(bptr0+4);
  fv4 b1l=*(const fv4*)bptr1, b1h=*(const fv4*)(bptr1+4);
  const int NK = HID/32;
  for (int kt=0; kt<NK; kt++){
    __syncthreads();
    *(h8*)&ldsA[ldsx(srow,    q8)] = cvt8(a0l,a0h);
    *(h8*)&ldsA[ldsx(srow+64, q8)] = cvt8(a1l,a1h);
    *(h8*)&ldsB[ldsx(srow,    q8)] = cvt8(b0l,b0h);
    *(h8*)&ldsB[ldsx(srow+64, q8)] = cvt8(b1l,b1h);
    __syncthreads();
    if (kt+1<NK){
      const int k1 = (kt+1)*32;
      a0l=*(const fv4*)(aptr0+k1); a0h=*(const fv4*)(aptr0+k1+4);
      a1l=*(const fv4*)(aptr1+k1); a1h=*(const fv4*)(aptr1+k1+4);
      b0l=*(const fv4*)(bptr0+k1); b0h=*(const fv4*)(bptr0+k1+4);
      b1l=*(const fv4*)(bptr1+k1); b1h=*(const fv4*)(bptr1+k1+4);
    }
    h8 af[4], bfr[4];
    const int kq = lane>>4;
    #pragma unroll
    for (int m=0;m<4;m++){
      const int r = wr*64+m*16+(lane&15);
      af[m]  = *(const h8*)&ldsA[ldsx(r, kq)];
    }
    #pragma unroll
    for (int n2=0;n2<4;n2++){
      const int r = wc*64+n2*16+(lane&15);
      bfr[n2] = *(const h8*)&ldsB[ldsx(r, kq)];
    }
    #pragma unroll
    for (int m=0;m<4;m++)
      #pragma unroll
      for (int n2=0;n2<4;n2++)
        acc[m][n2]=__builtin_amdgcn_mfma_f32_16x16x32_f16(af[m],bfr[n2],acc[m][n2],0,0,0);
  }

  const int r0 = by*128 + wr*64;
  const int c0 = bx*128 + wc*64;
  #pragma unroll
  for (int n2=0;n2<4;n2++){
    const int col = c0 + n2*16 + (lane&15);
    const float bv = bias[(size_t)expert*EW_ + col];
    #pragma unroll
    for (int m=0;m<4;m++){
      #pragma unroll
      for (int j=0;j<4;j++){
        const int row = r0 + m*16 + (lane>>4)*4 + j;
        const size_t addr = ((size_t)row*TD_ + t)*EW_ + col;
        float vacc = acc[m][n2][j] + bv;
        if (IS_GATE){
          float up = h2f_bits(act[addr]);
          float g  = fminf(vacc, 7.0f);
          up = fminf(fmaxf(up,-7.0f),7.0f);
          float glu = g * (1.f/(1.f+__expf(-g*1.702f)));
          float a = (up+1.f)*glu;
          const int rown = GATHER ? tok[t*MAXNNZ_+row] : row;
          a *= rw[(size_t)rown*NE_ + expert];
          if (col>=ORIG_) a=0.f;
          act[addr]=f2h_bits(a);
        } else {
          act[addr]=f2h_bits(vacc);
        }
      }
    }
  }
}

// ------- down GEMM: out[n][h] += act[n][k] * D[h][k], atomics into d_out ----
template<bool GATHER>
__global__ __launch_bounds__(256) void k_down(const u16* __restrict__ act,
                                              const float* __restrict__ dw,
                                              const int* __restrict__ cdcs,
                                              const int* __restrict__ tok,
                                              float* __restrict__ outf)
{
  __shared__ __align__(16) u16 ldsA[128*LDSP];
  __shared__ __align__(16) u16 ldsB[128*LDSP];
  const int tid=threadIdx.x, lane=tid&63, wid=tid>>6;
  const int bx=blockIdx.x, by=blockIdx.y, z=blockIdx.z;
  const int srow=tid>>2, q8=tid&3;
  const int tstart = GATHER ? z : z*2;
  const int NK = (GATHER ? 1 : 2) * (EW_/32);
  const int listoff = GATHER ? 8 : 0;

  const u16* aptr0 = act + ((size_t)(by*128+srow)*TD_ + tstart)*EW_ + q8*8;
  const u16* aptr1 = aptr0 + (size_t)64*TD_*EW_;
  const float* b0 = dw + (size_t)(bx*128 + srow)*NEWTOT + q8*8;
  const float* b1 = b0 + (size_t)64*NEWTOT;

  f32x4 acc[4][4];
  #pragma unroll
  for (int i=0;i<4;i++)
    #pragma unroll
    for (int j=0;j<4;j++)
      #pragma unroll
      for (int q=0;q<4;q++) acc[i][j][q]=0.f;

  const int wr=wid>>1, wc=wid&1;
  const int ex0 = cdcs[listoff + tstart];
  s16x8 ra0 = *(const s16x8*)aptr0;
  s16x8 ra1 = *(const s16x8*)aptr1;
  fv4 c0l=*(const fv4*)(b0+(size_t)ex0*EW_), c0h=*(const fv4*)(b0+(size_t)ex0*EW_+4);
  fv4 c1l=*(const fv4*)(b1+(size_t)ex0*EW_), c1h=*(const fv4*)(b1+(size_t)ex0*EW_+4);
  for (int kt=0; kt<NK; kt++){
    __syncthreads();
    *(s16x8*)&ldsA[ldsx(srow,    q8)] = ra0;
    *(s16x8*)&ldsA[ldsx(srow+64, q8)] = ra1;
    *(h8*)&ldsB[ldsx(srow,    q8)] = cvt8(c0l,c0h);
    *(h8*)&ldsB[ldsx(srow+64, q8)] = cvt8(c1l,c1h);
    __syncthreads();
    if (kt+1<NK){
      const int k1 = (kt+1)*32;
      const int hop = (k1>=EW_) ? 1 : 0;
      const int e1 = k1 - hop*EW_;
      const size_t bo = (size_t)cdcs[listoff + tstart + hop]*EW_ + e1;
      ra0 = *(const s16x8*)(aptr0 + k1);
      ra1 = *(const s16x8*)(aptr1 + k1);
      c0l = *(const fv4*)(b0+bo); c0h = *(const fv4*)(b0+bo+4);
      c1l = *(const fv4*)(b1+bo); c1h = *(const fv4*)(b1+bo+4);
    }
    h8 af[4], bfr[4];
    const int kq = lane>>4;
    #pragma unroll
    for (int m=0;m<4;m++){
      const int r = wr*64+m*16+(lane&15);
      af[m]  = *(const h8*)&ldsA[ldsx(r, kq)];
    }
    #pragma unroll
    for (int n2=0;n2<4;n2++){
      const int r = wc*64+n2*16+(lane&15);
      bfr[n2] = *(const h8*)&ldsB[ldsx(r, kq)];
    }
    #pragma unroll
    for (int m=0;m<4;m++)
      #pragma unroll
      for (int n2=0;n2<4;n2++)
        acc[m][n2]=__builtin_amdgcn_mfma_f32_16x16x32_f16(af[m],bfr[n2],acc[m][n2],0,0,0);
  }

  const int r0=by*128+wr*64, c0=bx*128+wc*64;
  #pragma unroll
  for (int m=0;m<4;m++){
    #pragma unroll
    for (int j=0;j<4;j++){
      const int row = r0 + m*16 + (lane>>4)*4 + j;
      const int orow = GATHER ? tok[z*MAXNNZ_+row] : row;
      #pragma unroll
      for (int n2=0;n2<4;n2++){
        const int col = c0 + n2*16 + (lane&15);
        atomicAdd(outf + (size_t)orow*HID + col, acc[m][n2][j]);
      }
    }
  }
}

extern "C" void kernel_launch(void* const* d_in, const int* in_sizes, int n_in,
                              void* d_out, int out_size, void* d_ws, size_t ws_size,
                              hipStream_t stream)
{
  const float* x  = (const float*)d_in[0];
  const float* gw = (const float*)d_in[1];
  const float* u  = (const float*)d_in[2];
  const float* g  = (const float*)d_in[3];
  const float* dw = (const float*)d_in[4];
  const float* ub = (const float*)d_in[5];
  const float* gb = (const float*)d_in[6];

  char* ws = (char*)d_ws;
  size_t off = 0;
  auto alloc = [&](size_t bytes)->void*{ void* p = ws + off; off += (bytes + 255) & ~(size_t)255; return p; };
  float* rw    = (float*)alloc((size_t)BS_*NE_*4);
  float* rwf   = (float*)alloc((size_t)BS_*NE_*4);
  int*   counts= (int*)  alloc(NE_*4);
  size_t zero_span = off;                 // rw + rwf + counts must start zeroed
  int*   cdcs  = (int*)  alloc(16*4);
  int*   tok   = (int*)  alloc(8*MAXNNZ_*4);
  u16*   actd  = (u16*)  alloc((size_t)BS_*TD_*EW_*2);
  u16*   acts  = (u16*)  alloc((size_t)MAXNNZ_*TD_*EW_*2);
  if (off > ws_size) return;

  hipMemsetAsync(ws, 0, zero_span, stream);
  hipMemsetAsync(d_out, 0, (size_t)BS_*HID*4, stream);   // f32 output accumulator

  k_gate  <<<BS_/4, 256, 0, stream>>>(x, gw, rw, rwf, counts);
  k_rank  <<<1,     64,  0, stream>>>(counts, cdcs);
  k_select<<<8,     256, 0, stream>>>(rwf, cdcs, tok);

  dim3 gdense(EW_/128, BS_/128, TD_);      // (23, 8, 8)
  dim3 gsparse(EW_/128, MAXNNZ_/128, TD_); // (23, 2, 8)
  k_upgate<false,false><<<gdense, 256, 0, stream>>>(x, u, ub, rw, cdcs, tok, actd);
  k_upgate<true ,false><<<gdense, 256, 0, stream>>>(x, g, gb, rw, cdcs, tok, actd);
  k_upgate<false,true ><<<gsparse,256, 0, stream>>>(x, u, ub, rw, cdcs, tok, acts);
  k_upgate<true ,true ><<<gsparse,256, 0, stream>>>(x, g, gb, rw, cdcs, tok, acts);

  k_down<false><<<dim3(HID/128, BS_/128, 4),     256, 0, stream>>>(actd, dw, cdcs, tok, (float*)d_out);
  k_down<true ><<<dim3(HID/128, MAXNNZ_/128, 8), 256, 0, stream>>>(acts, dw, cdcs, tok, (float*)d_out);
}

// Round 8
// 738.243 us; speedup vs baseline: 1.7162x; 1.7162x over previous
//
#include <hip/hip_runtime.h>

#define HID 2048
#define NE_ 32
#define EW_ 2944
#define ORIG_ 2880
#define TOPK_ 4
#define TD_ 8
#define MAXNNZ_ 256
#define BS_ 1024
#define NEWTOT (NE_*EW_)
#define LDSP 40   // padded row stride in halves: 80B, balanced b128 banks

typedef unsigned short u16;
typedef _Float16 h8  __attribute__((ext_vector_type(8)));
typedef float  f32x4 __attribute__((ext_vector_type(4)));
typedef float  fv4   __attribute__((ext_vector_type(4)));
typedef short  s16x8 __attribute__((ext_vector_type(8)));

__device__ __forceinline__ u16 f2h_bits(float f){
  union{ _Float16 h; u16 u; } c; c.h = (_Float16)f; return c.u;
}
__device__ __forceinline__ float f16q(float f){ return (float)(_Float16)f; }

__device__ __forceinline__ h8 cvt8(fv4 a, fv4 b){
  h8 r;
  r[0]=(_Float16)a[0]; r[1]=(_Float16)a[1]; r[2]=(_Float16)a[2]; r[3]=(_Float16)a[3];
  r[4]=(_Float16)b[0]; r[5]=(_Float16)b[1]; r[6]=(_Float16)b[2]; r[7]=(_Float16)b[3];
  return r;
}
__device__ __forceinline__ int ldsx(int row, int q8){ return row*LDSP + q8*8; }

// ---------------- gating: f32 in, f16-quantized logits, top4 ----------------
__global__ __launch_bounds__(256) void k_gate(const float* __restrict__ x,
                                              const float* __restrict__ gw,
                                              float* __restrict__ rw,
                                              float* __restrict__ rwf,
                                              int* __restrict__ counts)
{
  __shared__ float slog[4][NE_];
  const int tid = threadIdx.x, wid = tid>>6, lane = tid&63;
  const int n = blockIdx.x*4 + wid;
  const float* xr = x + (size_t)n*HID + lane*32;
  float xf[32];
  #pragma unroll
  for (int i=0;i<8;i++){
    fv4 v = *(const fv4*)(xr + i*4);
    #pragma unroll
    for (int j=0;j<4;j++) xf[i*4+j] = v[j];
  }
  for (int e=0;e<NE_;e++){
    const float* gr = gw + (size_t)e*HID + lane*32;
    float p = 0.f;
    #pragma unroll
    for (int i=0;i<8;i++){
      fv4 v = *(const fv4*)(gr + i*4);
      #pragma unroll
      for (int j=0;j<4;j++) p += xf[i*4+j]*v[j];
    }
    #pragma unroll
    for (int s=32;s>0;s>>=1) p += __shfl_xor(p, s);
    if (lane==0) slog[wid][e] = f16q(p);   // reference rounds matmul to f16
  }
  if (lane==0){
    float mx=-1e30f;
    for (int e=0;e<NE_;e++) mx = fmaxf(mx, slog[wid][e]);
    float pr[NE_]; float sum=0.f;
    for (int e=0;e<NE_;e++){ float v=__expf(slog[wid][e]-mx); pr[e]=v; sum+=v; }
    for (int e=0;e<NE_;e++) pr[e] = pr[e]/sum;
    int   idx[TOPK_]; float val[TOPK_]; bool used[NE_];
    for (int e=0;e<NE_;e++) used[e]=false;
    float vs=0.f;
    for (int k=0;k<TOPK_;k++){
      float best=-1.f; int bi=0;
      for (int e=0;e<NE_;e++) if(!used[e] && pr[e]>best){best=pr[e];bi=e;}
      used[bi]=true; idx[k]=bi; val[k]=best; vs+=best;
    }
    float* rwr  = rw  + (size_t)n*NE_;
    float* rwfr = rwf + (size_t)n*NE_;
    for (int k=0;k<TOPK_;k++){
      float vraw = val[k]/vs;
      float q = f16q(vraw);            // reference: rw = sparse_rw.astype(f16)
      rwr[idx[k]]  = q;
      rwfr[idx[k]] = vraw;             // f32, for top-256 ranking (matches jax)
      if (q!=0.f) atomicAdd(counts+idx[k], 1);
    }
  }
}

// ---------------- rank experts by count (desc), tie -> lower index ----------
__global__ void k_rank(const int* __restrict__ counts, int* __restrict__ cdcs)
{
  if (threadIdx.x==0){
    int cnt[NE_]; bool used[NE_];
    for (int e=0;e<NE_;e++){ cnt[e]=counts[e]; used[e]=false; }
    for (int k=0;k<16;k++){
      int best=-1, bi=0;
      for (int e=0;e<NE_;e++) if(!used[e] && cnt[e]>best){best=cnt[e];bi=e;}
      used[bi]=true; cdcs[k]=bi;
    }
  }
}

// ------- per-expert token lists: dense = rw!=0 (index order) + count;
//         sparse = exact top-256 by (f32 value desc, index asc) -------------
__global__ __launch_bounds__(256) void k_lists(const float* __restrict__ rw,
                                               const float* __restrict__ rwf,
                                               const int* __restrict__ cdcs,
                                               int* __restrict__ tok_all,
                                               int* __restrict__ cnt_all)
{
  __shared__ float v[BS_];
  const int z = blockIdx.x;
  const int e = cdcs[z];
  const int tid = threadIdx.x;
  for (int i=tid;i<BS_;i+=256) tok_all[z*BS_+i] = 0;
  if (z < 8){
    for (int i=tid;i<BS_;i+=256) v[i] = rw[(size_t)i*NE_ + e];
    __syncthreads();
    for (int i=tid;i<BS_;i+=256){
      if (v[i] != 0.f){
        int r=0;
        for (int m=0;m<i;m++) r += (v[m]!=0.f);
        tok_all[z*BS_+r] = i;
      }
    }
    if (tid==0){
      int c=0;
      for (int m=0;m<BS_;m++) c += (v[m]!=0.f);
      cnt_all[z]=c;
    }
  } else {
    for (int i=tid;i<BS_;i+=256) v[i] = rwf[(size_t)i*NE_ + e];
    __syncthreads();
    for (int i=tid;i<BS_;i+=256){
      float vi=v[i]; int r=0;
      for (int m=0;m<BS_;m++){
        float vm=v[m];
        r += (vm>vi) || (vm==vi && m<i);
      }
      if (r<MAXNNZ_) tok_all[z*BS_+r]=i;
    }
    if (tid==0) cnt_all[z]=MAXNNZ_;
  }
}

// ------- fused up+gate gathered GEMM, 128x128 tile, 8 waves of 64x32 -------
__global__ __launch_bounds__(512) void k_fused(const float* __restrict__ x,
                                               const float* __restrict__ uw,
                                               const float* __restrict__ gww,
                                               const float* __restrict__ ub,
                                               const float* __restrict__ gb,
                                               const float* __restrict__ rw,
                                               const int* __restrict__ cdcs,
                                               const int* __restrict__ tok_all,
                                               const int* __restrict__ cnt_all,
                                               u16* __restrict__ act)
{
  const int z=blockIdx.z, bx=blockIdx.x, by=blockIdx.y;
  const int cnt = cnt_all[z];
  if (by*128 >= cnt) return;
  const int e = cdcs[z];
  __shared__ __align__(16) u16 ldsA[128*LDSP];
  __shared__ __align__(16) u16 ldsU[128*LDSP];
  __shared__ __align__(16) u16 ldsG[128*LDSP];
  const int tid=threadIdx.x, lane=tid&63, w=tid>>6;
  const int wr=w>>2, wc=w&3;
  const int srow=tid>>2, q8=tid&3;
  const int gi = by*128 + srow;
  const int token = tok_all[z*BS_ + gi];
  const float* aptr = x + (size_t)token*HID + q8*8;
  const size_t bro = ((size_t)e*EW_ + bx*128 + srow)*HID + q8*8;
  const float* uptr = uw  + bro;
  const float* gptr = gww + bro;

  f32x4 au[4][2], ag[4][2];
  #pragma unroll
  for (int i=0;i<4;i++)
    #pragma unroll
    for (int j=0;j<2;j++)
      #pragma unroll
      for (int q=0;q<4;q++){ au[i][j][q]=0.f; ag[i][j][q]=0.f; }

  fv4 aL=*(const fv4*)aptr, aH=*(const fv4*)(aptr+4);
  fv4 uL=*(const fv4*)uptr, uH=*(const fv4*)(uptr+4);
  fv4 gL=*(const fv4*)gptr, gH=*(const fv4*)(gptr+4);
  const int NK = HID/32;
  for (int kt=0; kt<NK; kt++){
    __syncthreads();
    *(h8*)&ldsA[ldsx(srow,q8)] = cvt8(aL,aH);
    *(h8*)&ldsU[ldsx(srow,q8)] = cvt8(uL,uH);
    *(h8*)&ldsG[ldsx(srow,q8)] = cvt8(gL,gH);
    __syncthreads();
    if (kt+1<NK){
      const int k1=(kt+1)*32;
      aL=*(const fv4*)(aptr+k1); aH=*(const fv4*)(aptr+k1+4);
      uL=*(const fv4*)(uptr+k1); uH=*(const fv4*)(uptr+k1+4);
      gL=*(const fv4*)(gptr+k1); gH=*(const fv4*)(gptr+k1+4);
    }
    const int kq = lane>>4;
    h8 af[4], fu[2], fg[2];
    #pragma unroll
    for (int m=0;m<4;m++) af[m] = *(const h8*)&ldsA[ldsx(wr*64+m*16+(lane&15), kq)];
    #pragma unroll
    for (int n2=0;n2<2;n2++){
      fu[n2] = *(const h8*)&ldsU[ldsx(wc*32+n2*16+(lane&15), kq)];
      fg[n2] = *(const h8*)&ldsG[ldsx(wc*32+n2*16+(lane&15), kq)];
    }
    #pragma unroll
    for (int m=0;m<4;m++)
      #pragma unroll
      for (int n2=0;n2<2;n2++){
        au[m][n2]=__builtin_amdgcn_mfma_f32_16x16x32_f16(af[m],fu[n2],au[m][n2],0,0,0);
        ag[m][n2]=__builtin_amdgcn_mfma_f32_16x16x32_f16(af[m],fg[n2],ag[m][n2],0,0,0);
      }
  }

  #pragma unroll
  for (int n2=0;n2<2;n2++){
    const int col = bx*128 + wc*32 + n2*16 + (lane&15);
    const float ubv = ub[(size_t)e*EW_ + col];
    const float gbv = gb[(size_t)e*EW_ + col];
    #pragma unroll
    for (int m=0;m<4;m++){
      #pragma unroll
      for (int j=0;j<4;j++){
        const int il = wr*64 + m*16 + (lane>>4)*4 + j;
        const int i  = by*128 + il;
        float upv = f16q(au[m][n2][j] + ubv);
        float gtv = f16q(ag[m][n2][j] + gbv);
        float wv = 0.f;
        if (i < cnt) wv = rw[(size_t)tok_all[z*BS_+i]*NE_ + e];
        float gc = fminf(gtv, 7.0f);
        float uc = fminf(fmaxf(upv,-7.0f),7.0f);
        float glu = gc * (1.f/(1.f+__expf(-gc*1.702f)));
        float a = (uc+1.f)*glu*wv;
        if (col>=ORIG_) a=0.f;
        act[((size_t)z*BS_+i)*EW_ + col] = f2h_bits(a);
      }
    }
  }
}

// ------- gathered down GEMM: out[tok[i]][h] += act[i]·D[h], K=2944 ---------
__global__ __launch_bounds__(256) void k_down(const u16* __restrict__ act,
                                              const float* __restrict__ dw,
                                              const int* __restrict__ cdcs,
                                              const int* __restrict__ tok_all,
                                              const int* __restrict__ cnt_all,
                                              float* __restrict__ outf)
{
  const int z=blockIdx.z, bx=blockIdx.x, by=blockIdx.y;
  const int cnt = cnt_all[z];
  if (by*128 >= cnt) return;
  const int e = cdcs[z];
  __shared__ __align__(16) u16 ldsA[128*LDSP];
  __shared__ __align__(16) u16 ldsB[128*LDSP];
  const int tid=threadIdx.x, lane=tid&63, wid=tid>>6;
  const int srow=tid>>2, q8=tid&3;

  const u16* aptr0 = act + ((size_t)z*BS_ + by*128 + srow)*EW_ + q8*8;
  const u16* aptr1 = aptr0 + (size_t)64*EW_;
  const float* b0 = dw + (size_t)(bx*128 + srow)*NEWTOT + (size_t)e*EW_ + q8*8;
  const float* b1 = b0 + (size_t)64*NEWTOT;

  f32x4 acc[4][4];
  #pragma unroll
  for (int i=0;i<4;i++)
    #pragma unroll
    for (int j=0;j<4;j++)
      #pragma unroll
      for (int q=0;q<4;q++) acc[i][j][q]=0.f;

  const int wr=wid>>1, wc=wid&1;
  s16x8 ra0 = *(const s16x8*)aptr0;
  s16x8 ra1 = *(const s16x8*)aptr1;
  fv4 c0l=*(const fv4*)b0, c0h=*(const fv4*)(b0+4);
  fv4 c1l=*(const fv4*)b1, c1h=*(const fv4*)(b1+4);
  const int NK = EW_/32;
  for (int kt=0; kt<NK; kt++){
    __syncthreads();
    *(s16x8*)&ldsA[ldsx(srow,   q8)] = ra0;
    *(s16x8*)&ldsA[ldsx(srow+64,q8)] = ra1;
    *(h8*)&ldsB[ldsx(srow,   q8)] = cvt8(c0l,c0h);
    *(h8*)&ldsB[ldsx(srow+64,q8)] = cvt8(c1l,c1h);
    __syncthreads();
    if (kt+1<NK){
      const int k1 = (kt+1)*32;
      ra0 = *(const s16x8*)(aptr0 + k1);
      ra1 = *(const s16x8*)(aptr1 + k1);
      c0l = *(const fv4*)(b0+k1); c0h = *(const fv4*)(b0+k1+4);
      c1l = *(const fv4*)(b1+k1); c1h = *(const fv4*)(b1+k1+4);
    }
    h8 af[4], bfr[4];
    const int kq = lane>>4;
    #pragma unroll
    for (int m=0;m<4;m++)   af[m]  = *(const h8*)&ldsA[ldsx(wr*64+m*16+(lane&15), kq)];
    #pragma unroll
    for (int n2=0;n2<4;n2++) bfr[n2] = *(const h8*)&ldsB[ldsx(wc*64+n2*16+(lane&15), kq)];
    #pragma unroll
    for (int m=0;m<4;m++)
      #pragma unroll
      for (int n2=0;n2<4;n2++)
        acc[m][n2]=__builtin_amdgcn_mfma_f32_16x16x32_f16(af[m],bfr[n2],acc[m][n2],0,0,0);
  }

  #pragma unroll
  for (int m=0;m<4;m++){
    #pragma unroll
    for (int j=0;j<4;j++){
      const int il = wr*64 + m*16 + (lane>>4)*4 + j;
      const int orow = tok_all[z*BS_ + by*128 + il];
      #pragma unroll
      for (int n2=0;n2<4;n2++){
        const int col = bx*128 + wc*64 + n2*16 + (lane&15);
        atomicAdd(outf + (size_t)orow*HID + col, acc[m][n2][j]);
      }
    }
  }
}

extern "C" void kernel_launch(void* const* d_in, const int* in_sizes, int n_in,
                              void* d_out, int out_size, void* d_ws, size_t ws_size,
                              hipStream_t stream)
{
  const float* x  = (const float*)d_in[0];
  const float* gw = (const float*)d_in[1];
  const float* u  = (const float*)d_in[2];
  const float* g  = (const float*)d_in[3];
  const float* dw = (const float*)d_in[4];
  const float* ub = (const float*)d_in[5];
  const float* gb = (const float*)d_in[6];

  char* ws = (char*)d_ws;
  size_t off = 0;
  auto alloc = [&](size_t bytes)->void*{ void* p = ws + off; off += (bytes + 255) & ~(size_t)255; return p; };
  float* rw     = (float*)alloc((size_t)BS_*NE_*4);
  float* rwf    = (float*)alloc((size_t)BS_*NE_*4);
  int*   counts = (int*)  alloc(NE_*4);
  size_t zero_span = off;                 // rw + rwf + counts must start zeroed
  int*   cdcs   = (int*)  alloc(16*4);
  int*   tok_all= (int*)  alloc((size_t)16*BS_*4);
  int*   cnt_all= (int*)  alloc(16*4);
  u16*   act    = (u16*)  alloc((size_t)16*BS_*EW_*2);
  if (off > ws_size) return;

  hipMemsetAsync(ws, 0, zero_span, stream);
  hipMemsetAsync(d_out, 0, (size_t)BS_*HID*4, stream);   // f32 output accumulator

  k_gate <<<BS_/4, 256, 0, stream>>>(x, gw, rw, rwf, counts);
  k_rank <<<1,     64,  0, stream>>>(counts, cdcs);
  k_lists<<<16,    256, 0, stream>>>(rw, rwf, cdcs, tok_all, cnt_all);

  k_fused<<<dim3(EW_/128, 8, 16), 512, 0, stream>>>(x, u, g, ub, gb, rw,
                                                    cdcs, tok_all, cnt_all, act);
  k_down <<<dim3(HID/128, 8, 16), 256, 0, stream>>>(act, dw, cdcs, tok_all,
                                                    cnt_all, (float*)d_out);
}